// Round 1
// baseline (158.314 us; speedup 1.0000x reference)
//
#include <hip/hip_runtime.h>
#include <hip/hip_bf16.h>

// Problem: B=8, C=512, H=W=64, NH=8, HD=64, WIN=64, NW=64.
// Key fact: reference reshapes (B,C,H,W) RAW to (B, NW, WIN, C) -> the token
// matrix is x reinterpreted as [32768][512] fp32, contiguous. So:
//   phase 1: QKV GEMM  M=32768 K=512 N=1536 (W row-major == B^T layout)
//   phase 2: per (window, head): S=Q@K^T*scale(+folded)+Bbias, softmax, P@V
// ws layout: [0,1.5MB) Wcat bf16; Q @2MiB (+32MiB); K @34MiB; V^T @66MiB. ~98MiB.

typedef __attribute__((ext_vector_type(8))) short bf16x8;
typedef __attribute__((ext_vector_type(4))) float f32x4;

#define GLDS(gp, lp) __builtin_amdgcn_global_load_lds( \
    (const __attribute__((address_space(1))) unsigned int*)(gp), \
    (__attribute__((address_space(3))) unsigned int*)(lp), 16, 0, 0)

__device__ __forceinline__ unsigned short f2bf(float f) {
  union { float f; unsigned int u; } v; v.f = f;
  unsigned int r = v.u + 0x7fffu + ((v.u >> 16) & 1u);  // RNE
  return (unsigned short)(r >> 16);
}

// ---------------- prep: W{q,k,v} fp32 -> Wcat bf16 [1536][512] ----------------
__global__ __launch_bounds__(256) void prep_weights(
    const float* __restrict__ Wq, const float* __restrict__ Wk,
    const float* __restrict__ Wv, unsigned short* __restrict__ Wc) {
  int i = blockIdx.x * 256 + threadIdx.x;      // 196608 threads, 4 elems each
  int n = i >> 7;                              // 0..1535
  int kk = (i & 127) << 2;                     // 0..508
  const float* src = (n < 512) ? Wq : (n < 1024 ? Wk : Wv);
  float4 v = *(const float4*)(src + (size_t)(n & 511) * 512 + kk);
  ushort4 o;
  o.x = f2bf(v.x); o.y = f2bf(v.y); o.z = f2bf(v.z); o.w = f2bf(v.w);
  *(ushort4*)(Wc + (size_t)n * 512 + kk) = o;
}

// ---------------- QKV GEMM (m97-style: 128x128 tile, BK=32) ----------------
// grid (12, 256): x = n-tile, y = m-tile. 256 thr = 4 waves, each 64x64 out.
// B staged with global_load_lds (bf16, linear LDS); A reg-staged fp32->bf16.
// Epilogue: +bias, Q pre-scaled by 1/8; Q,K stored [win][h][t][d]; V stored
// TRANSPOSED [win][h][d][t] so attention's B-operand reads are contiguous.
__global__ __launch_bounds__(256) void qkv_gemm(
    const float* __restrict__ X, const unsigned short* __restrict__ Wc,
    const float* __restrict__ bq, const float* __restrict__ bk,
    const float* __restrict__ bv,
    unsigned short* __restrict__ Qo, unsigned short* __restrict__ Ko,
    unsigned short* __restrict__ Vo) {
  __shared__ __align__(16) unsigned short As[2][128 * 32];
  __shared__ __align__(16) unsigned short Bs[2][128 * 32];

  const int tid  = threadIdx.x;
  const int lane = tid & 63;
  const int wid  = tid >> 6;
  const int n0 = blockIdx.x * 128;
  const int m0 = blockIdx.y * 128;
  const int wm = (wid >> 1) * 64;
  const int wn = (wid & 1) * 64;

  // A staging: thread covers row ar, 16-float half ac of the 32-wide k-tile
  const int ar = tid >> 1;
  const int ac = (tid & 1) * 16;
  const float* aptr = X + (size_t)(m0 + ar) * 512 + ac;

  // B staging: per wave 2 GLDS instrs of 1KB; lane -> row (lane>>2), 16B chunk (lane&3)
  const unsigned short* bg0 =
      Wc + (size_t)(n0 + wid * 32 + (lane >> 2)) * 512 + (lane & 3) * 8;
  const unsigned short* bg1 = bg0 + 16 * 512;

  f32x4 acc[4][4];
#pragma unroll
  for (int i = 0; i < 4; ++i)
#pragma unroll
    for (int j = 0; j < 4; ++j) acc[i][j] = (f32x4){0.f, 0.f, 0.f, 0.f};

  // prologue: stage k-tile 0 into buffer 0
  {
    float4 f0 = *(const float4*)(aptr + 0);
    float4 f1 = *(const float4*)(aptr + 4);
    float4 f2 = *(const float4*)(aptr + 8);
    float4 f3 = *(const float4*)(aptr + 12);
    __align__(16) unsigned short u[16];
    u[0]=f2bf(f0.x); u[1]=f2bf(f0.y); u[2]=f2bf(f0.z); u[3]=f2bf(f0.w);
    u[4]=f2bf(f1.x); u[5]=f2bf(f1.y); u[6]=f2bf(f1.z); u[7]=f2bf(f1.w);
    u[8]=f2bf(f2.x); u[9]=f2bf(f2.y); u[10]=f2bf(f2.z); u[11]=f2bf(f2.w);
    u[12]=f2bf(f3.x); u[13]=f2bf(f3.y); u[14]=f2bf(f3.z); u[15]=f2bf(f3.w);
    unsigned short* d = &As[0][ar * 32 + ac];
    *(bf16x8*)(d)     = *(const bf16x8*)(u);
    *(bf16x8*)(d + 8) = *(const bf16x8*)(u + 8);
    GLDS(bg0, &Bs[0][(wid * 32) * 32]);
    GLDS(bg1, &Bs[0][(wid * 32 + 16) * 32]);
  }
  __syncthreads();

  int cur = 0;
  for (int kt = 0; kt < 16; ++kt) {
    float4 f0, f1, f2, f3;
    if (kt < 15) {  // issue next-tile loads before compute (T3-minimal 2-phase)
      const float* ap = aptr + (kt + 1) * 32;
      f0 = *(const float4*)(ap + 0);
      f1 = *(const float4*)(ap + 4);
      f2 = *(const float4*)(ap + 8);
      f3 = *(const float4*)(ap + 12);
      GLDS(bg0 + (kt + 1) * 32, &Bs[cur ^ 1][(wid * 32) * 32]);
      GLDS(bg1 + (kt + 1) * 32, &Bs[cur ^ 1][(wid * 32 + 16) * 32]);
    }
    bf16x8 a[4], b[4];
#pragma unroll
    for (int t = 0; t < 4; ++t) {
      a[t] = *(const bf16x8*)(&As[cur][(wm + t * 16 + (lane & 15)) * 32 + (lane >> 4) * 8]);
      b[t] = *(const bf16x8*)(&Bs[cur][(wn + t * 16 + (lane & 15)) * 32 + (lane >> 4) * 8]);
    }
#pragma unroll
    for (int mt = 0; mt < 4; ++mt)
#pragma unroll
      for (int nt = 0; nt < 4; ++nt)
        acc[mt][nt] = __builtin_amdgcn_mfma_f32_16x16x32_bf16(
            a[mt], b[nt], acc[mt][nt], 0, 0, 0);
    if (kt < 15) {  // convert + ds_write A into next buffer
      __align__(16) unsigned short u[16];
      u[0]=f2bf(f0.x); u[1]=f2bf(f0.y); u[2]=f2bf(f0.z); u[3]=f2bf(f0.w);
      u[4]=f2bf(f1.x); u[5]=f2bf(f1.y); u[6]=f2bf(f1.z); u[7]=f2bf(f1.w);
      u[8]=f2bf(f2.x); u[9]=f2bf(f2.y); u[10]=f2bf(f2.z); u[11]=f2bf(f2.w);
      u[12]=f2bf(f3.x); u[13]=f2bf(f3.y); u[14]=f2bf(f3.z); u[15]=f2bf(f3.w);
      unsigned short* d = &As[cur ^ 1][ar * 32 + ac];
      *(bf16x8*)(d)     = *(const bf16x8*)(u);
      *(bf16x8*)(d + 8) = *(const bf16x8*)(u + 8);
    }
    __syncthreads();
    cur ^= 1;
  }

  // epilogue: +bias, scale Q by 1/sqrt(64); write bf16
  const int p = n0 >> 9;                       // 0:Q 1:K 2:V (tile never spans)
  const float* bias = (p == 0) ? bq : (p == 1) ? bk : bv;
  const float qs = (p == 0) ? 0.125f : 1.0f;
  const int win = (m0 + wm) >> 6;              // wave's rows lie in one window
  const int nb = (n0 & 511) + wn;
#pragma unroll
  for (int nt = 0; nt < 4; ++nt) {
    const int ncol = nb + nt * 16 + (lane & 15);   // channel within tensor
    const float bsv = bias[ncol];
    const int h = ncol >> 6, dch = ncol & 63;
    const size_t hb = (size_t)(win * 8 + h) * 4096;
#pragma unroll
    for (int mt = 0; mt < 4; ++mt) {
      const int t0 = mt * 16 + ((lane >> 4) << 2);
      if (p < 2) {
        unsigned short* dst = ((p == 0) ? Qo : Ko) + hb;
#pragma unroll
        for (int rr = 0; rr < 4; ++rr)
          dst[(size_t)(t0 + rr) * 64 + dch] = f2bf((acc[mt][nt][rr] + bsv) * qs);
      } else {
        ushort4 pk;   // 4 consecutive t for fixed d -> packed 8B store into V^T
        pk.x = f2bf(acc[mt][nt][0] + bsv);
        pk.y = f2bf(acc[mt][nt][1] + bsv);
        pk.z = f2bf(acc[mt][nt][2] + bsv);
        pk.w = f2bf(acc[mt][nt][3] + bsv);
        *(ushort4*)(Vo + hb + (size_t)dch * 64 + t0) = pk;
      }
    }
  }
}

// ---------------- attention: 1 wave per (window, head) ----------------
__global__ __launch_bounds__(64) void attn_win(
    const unsigned short* __restrict__ Qp, const unsigned short* __restrict__ Kp,
    const unsigned short* __restrict__ Vp, const float* __restrict__ Bb,
    float* __restrict__ out) {
  __shared__ __align__(16) unsigned short P[64 * 72];  // pad 72: conflict-free
  const int lane = threadIdx.x;
  const int win = blockIdx.x >> 3;
  const int h   = blockIdx.x & 7;
  const size_t base = (size_t)(win * 8 + h) * 4096;
  const unsigned short* q = Qp + base;
  const unsigned short* k = Kp + base;
  const unsigned short* v = Vp + base;   // V^T: [d][t]
  const int lr = lane & 15;
  const int hi = lane >> 4;

  bf16x8 qa[4][2], kb[4][2];
#pragma unroll
  for (int mt = 0; mt < 4; ++mt)
#pragma unroll
    for (int ks = 0; ks < 2; ++ks)
      qa[mt][ks] = *(const bf16x8*)(q + (size_t)(mt * 16 + lr) * 64 + ks * 32 + hi * 8);
#pragma unroll
  for (int nt = 0; nt < 4; ++nt)
#pragma unroll
    for (int ks = 0; ks < 2; ++ks)
      kb[nt][ks] = *(const bf16x8*)(k + (size_t)(nt * 16 + lr) * 64 + ks * 32 + hi * 8);

  f32x4 s[4][4];
#pragma unroll
  for (int mt = 0; mt < 4; ++mt)
#pragma unroll
    for (int nt = 0; nt < 4; ++nt) {
      s[mt][nt] = (f32x4){0.f, 0.f, 0.f, 0.f};
      s[mt][nt] = __builtin_amdgcn_mfma_f32_16x16x32_bf16(qa[mt][0], kb[nt][0], s[mt][nt], 0, 0, 0);
      s[mt][nt] = __builtin_amdgcn_mfma_f32_16x16x32_bf16(qa[mt][1], kb[nt][1], s[mt][nt], 0, 0, 0);
    }

  // + relative position bias (Q already carries the 1/8 scale)
#pragma unroll
  for (int mt = 0; mt < 4; ++mt)
#pragma unroll
    for (int nt = 0; nt < 4; ++nt)
#pragma unroll
      for (int rr = 0; rr < 4; ++rr)
        s[mt][nt][rr] += Bb[(mt * 16 + hi * 4 + rr) * 64 + nt * 16 + lr];

  // row softmax: row lives in the 16-lane group (cols = lane&15, 4 nt frags)
  float inv[4][4];
#pragma unroll
  for (int mt = 0; mt < 4; ++mt)
#pragma unroll
    for (int rr = 0; rr < 4; ++rr) {
      float m = fmaxf(fmaxf(s[mt][0][rr], s[mt][1][rr]),
                      fmaxf(s[mt][2][rr], s[mt][3][rr]));
      m = fmaxf(m, __shfl_xor(m, 1));
      m = fmaxf(m, __shfl_xor(m, 2));
      m = fmaxf(m, __shfl_xor(m, 4));
      m = fmaxf(m, __shfl_xor(m, 8));
      float sum = 0.f;
#pragma unroll
      for (int nt = 0; nt < 4; ++nt) {
        float e = __expf(s[mt][nt][rr] - m);
        s[mt][nt][rr] = e;
        sum += e;
      }
      sum += __shfl_xor(sum, 1);
      sum += __shfl_xor(sum, 2);
      sum += __shfl_xor(sum, 4);
      sum += __shfl_xor(sum, 8);
      inv[mt][rr] = 1.0f / sum;
    }

#pragma unroll
  for (int mt = 0; mt < 4; ++mt)
#pragma unroll
    for (int nt = 0; nt < 4; ++nt)
#pragma unroll
      for (int rr = 0; rr < 4; ++rr)
        P[(mt * 16 + hi * 4 + rr) * 72 + nt * 16 + lr] =
            f2bf(s[mt][nt][rr] * inv[mt][rr]);
  __syncthreads();

  bf16x8 pa[4][2], vb[4][2];
#pragma unroll
  for (int mt = 0; mt < 4; ++mt)
#pragma unroll
    for (int ks = 0; ks < 2; ++ks)
      pa[mt][ks] = *(const bf16x8*)(&P[(mt * 16 + lr) * 72 + ks * 32 + hi * 8]);
#pragma unroll
  for (int nt = 0; nt < 4; ++nt)
#pragma unroll
    for (int ks = 0; ks < 2; ++ks)
      vb[nt][ks] = *(const bf16x8*)(v + (size_t)(nt * 16 + lr) * 64 + ks * 32 + hi * 8);

  f32x4 o[4][4];
#pragma unroll
  for (int mt = 0; mt < 4; ++mt)
#pragma unroll
    for (int nt = 0; nt < 4; ++nt) {
      o[mt][nt] = (f32x4){0.f, 0.f, 0.f, 0.f};
      o[mt][nt] = __builtin_amdgcn_mfma_f32_16x16x32_bf16(pa[mt][0], vb[nt][0], o[mt][nt], 0, 0, 0);
      o[mt][nt] = __builtin_amdgcn_mfma_f32_16x16x32_bf16(pa[mt][1], vb[nt][1], o[mt][nt], 0, 0, 0);
    }

  float* op = out + (size_t)win * 32768 + h * 64;
#pragma unroll
  for (int mt = 0; mt < 4; ++mt)
#pragma unroll
    for (int nt = 0; nt < 4; ++nt)
#pragma unroll
      for (int rr = 0; rr < 4; ++rr)
        op[(size_t)(mt * 16 + hi * 4 + rr) * 512 + nt * 16 + lr] = o[mt][nt][rr];
}

extern "C" void kernel_launch(void* const* d_in, const int* in_sizes, int n_in,
                              void* d_out, int out_size, void* d_ws, size_t ws_size,
                              hipStream_t stream) {
  const float* x     = (const float*)d_in[0];
  const float* Wq    = (const float*)d_in[1];
  const float* bq    = (const float*)d_in[2];
  const float* Wk    = (const float*)d_in[3];
  const float* bk    = (const float*)d_in[4];
  const float* Wv    = (const float*)d_in[5];
  const float* bv    = (const float*)d_in[6];
  const float* Bbias = (const float*)d_in[7];
  float* out = (float*)d_out;

  // ws: Wcat @0 (1.5MiB) | Q @2MiB | K @34MiB | V^T @66MiB  (needs ~98MiB)
  unsigned short* Wc = (unsigned short*)d_ws;
  unsigned short* Q  = (unsigned short*)((char*)d_ws + (size_t)(2u << 20));
  unsigned short* K  = (unsigned short*)((char*)d_ws + (size_t)(34u << 20));
  unsigned short* V  = (unsigned short*)((char*)d_ws + (size_t)(66u << 20));

  prep_weights<<<dim3(768), dim3(256), 0, stream>>>(Wq, Wk, Wv, Wc);
  qkv_gemm<<<dim3(12, 256), dim3(256), 0, stream>>>(x, Wc, bq, bk, bv, Q, K, V);
  attn_win<<<dim3(4096), dim3(64), 0, stream>>>(Q, K, V, Bbias, out);
}

// Round 2
// 131.821 us; speedup vs baseline: 1.2010x; 1.2010x over previous
//
#include <hip/hip_runtime.h>
#include <hip/hip_bf16.h>

// B=8, C=512, H=W=64, NH=8, HD=64, WIN=64, NW=64.
// Reference reshapes (B,C,H,W) RAW to (B,NW,WIN,C): token matrix = x viewed
// as [32768][512] fp32 contiguous.
//   phase 0: convert X -> bf16 (32 MiB, L3-resident), W{q,k,v} -> Wcat bf16
//   phase 1: QKV GEMM M=32768 K=512 N=1536, pure bf16, GLDS both operands
//   phase 2: per (window,head): S=Q@K^T(+bias), softmax, P@V
// Fast ws layout: Wc@0 | Xb@2MiB | Q@36MiB | K@68MiB | V^T@100MiB (132MiB).
// Fallback (ws<132MiB): round-1 path (fp32 A staging), layout ends at 98MiB.

typedef __attribute__((ext_vector_type(8))) short bf16x8;
typedef __attribute__((ext_vector_type(4))) float f32x4;

#define GLDS(gp, lp) __builtin_amdgcn_global_load_lds( \
    (const __attribute__((address_space(1))) unsigned int*)(gp), \
    (__attribute__((address_space(3))) unsigned int*)(lp), 16, 0, 0)

__device__ __forceinline__ unsigned short f2bf(float f) {
  union { float f; unsigned int u; } v; v.f = f;
  unsigned int r = v.u + 0x7fffu + ((v.u >> 16) & 1u);  // RNE
  return (unsigned short)(r >> 16);
}

// ---------- prep (fast path): X fp32->bf16 and W{q,k,v} -> Wcat bf16 ----------
__global__ __launch_bounds__(256) void prep_convert(
    const float* __restrict__ X, const float* __restrict__ Wq,
    const float* __restrict__ Wk, const float* __restrict__ Wv,
    unsigned short* __restrict__ Xb, unsigned short* __restrict__ Wc) {
  const unsigned int i = blockIdx.x * 256 + threadIdx.x;
  const float* src;
  unsigned short* dst;
  if (i < 2097152u) {                       // X: 16.7M floats, 8 per thread
    src = X + (size_t)i * 8;
    dst = Xb + (size_t)i * 8;
  } else {                                  // Wcat: [1536][512]
    const unsigned int j = i - 2097152u;    // < 98304
    const unsigned int e = j * 8;
    const unsigned int n = e >> 9, kk = e & 511;
    src = ((n < 512) ? Wq : (n < 1024 ? Wk : Wv)) + (size_t)(n & 511) * 512 + kk;
    dst = Wc + (size_t)n * 512 + kk;
  }
  float4 f0 = *(const float4*)(src);
  float4 f1 = *(const float4*)(src + 4);
  __align__(16) unsigned short u[8];
  u[0] = f2bf(f0.x); u[1] = f2bf(f0.y); u[2] = f2bf(f0.z); u[3] = f2bf(f0.w);
  u[4] = f2bf(f1.x); u[5] = f2bf(f1.y); u[6] = f2bf(f1.z); u[7] = f2bf(f1.w);
  *(bf16x8*)(dst) = *(const bf16x8*)(u);
}

// ---------- prep (fallback): weights only ----------
__global__ __launch_bounds__(256) void prep_weights(
    const float* __restrict__ Wq, const float* __restrict__ Wk,
    const float* __restrict__ Wv, unsigned short* __restrict__ Wc) {
  int i = blockIdx.x * 256 + threadIdx.x;
  int n = i >> 7;
  int kk = (i & 127) << 2;
  const float* src = (n < 512) ? Wq : (n < 1024 ? Wk : Wv);
  float4 v = *(const float4*)(src + (size_t)(n & 511) * 512 + kk);
  ushort4 o;
  o.x = f2bf(v.x); o.y = f2bf(v.y); o.z = f2bf(v.z); o.w = f2bf(v.w);
  *(ushort4*)(Wc + (size_t)n * 512 + kk) = o;
}

// ---------- shared epilogue for both GEMM variants ----------
__device__ __forceinline__ void gemm_epilogue(
    f32x4 (&acc)[4][4], int n0, int m0, int wm, int wn, int lane,
    const float* bq, const float* bk, const float* bv,
    unsigned short* Qo, unsigned short* Ko, unsigned short* Vo) {
  const int p = n0 >> 9;                    // 0:Q 1:K 2:V
  const float* bias = (p == 0) ? bq : (p == 1) ? bk : bv;
  const float qs = (p == 0) ? 0.125f : 1.0f;
  const int win = (m0 + wm) >> 6;           // wave's 64 rows lie in one window
  const int nb = (n0 & 511) + wn;
#pragma unroll
  for (int nt = 0; nt < 4; ++nt) {
    const int ncol = nb + nt * 16 + (lane & 15);
    const float bsv = bias[ncol];
    const int h = ncol >> 6, dch = ncol & 63;
    const size_t hb = (size_t)(win * 8 + h) * 4096;
#pragma unroll
    for (int mt = 0; mt < 4; ++mt) {
      const int t0 = mt * 16 + ((lane >> 4) << 2);
      if (p < 2) {
        unsigned short* dst = ((p == 0) ? Qo : Ko) + hb;
#pragma unroll
        for (int rr = 0; rr < 4; ++rr)
          dst[(size_t)(t0 + rr) * 64 + dch] = f2bf((acc[mt][nt][rr] + bsv) * qs);
      } else {
        ushort4 pk;  // 4 consecutive t, fixed d -> 8B store into V^T [d][t]
        pk.x = f2bf(acc[mt][nt][0] + bsv);
        pk.y = f2bf(acc[mt][nt][1] + bsv);
        pk.z = f2bf(acc[mt][nt][2] + bsv);
        pk.w = f2bf(acc[mt][nt][3] + bsv);
        *(ushort4*)(Vo + hb + (size_t)dch * 64 + t0) = pk;
      }
    }
  }
}

// ---------- QKV GEMM fast path: all-bf16, GLDS for A and B ----------
// 1D grid 3072, XCD-chunked swizzle: XCD i gets works [i*384, (i+1)*384) so
// the 12 n-tiles of each m-tile share one L2 (X-tile fetched once per XCD).
__global__ __launch_bounds__(256) void qkv_gemm_bf16(
    const unsigned short* __restrict__ Xb, const unsigned short* __restrict__ Wc,
    const float* __restrict__ bq, const float* __restrict__ bk,
    const float* __restrict__ bv,
    unsigned short* __restrict__ Qo, unsigned short* __restrict__ Ko,
    unsigned short* __restrict__ Vo) {
  __shared__ __align__(16) unsigned short As[2][128 * 32];
  __shared__ __align__(16) unsigned short Bs[2][128 * 32];

  const int tid  = threadIdx.x;
  const int lane = tid & 63;
  const int wid  = tid >> 6;
  const int work = (int)(blockIdx.x & 7) * 384 + (int)(blockIdx.x >> 3);
  const int bx = work % 12, by = work / 12;
  const int n0 = bx * 128, m0 = by * 128;
  const int wm = (wid >> 1) * 64;
  const int wn = (wid & 1) * 64;

  // staging: per wave 2 GLDS-1KB per operand; lane -> row lane>>2, chunk lane&3
  const int srow = wid * 32 + (lane >> 2);
  const int scol = (lane & 3) * 8;
  const unsigned short* ag0 = Xb + (size_t)(m0 + srow) * 512 + scol;
  const unsigned short* bg0 = Wc + (size_t)(n0 + srow) * 512 + scol;
  const int ld0 = (wid * 32) * 32;          // LDS row offsets (elements)
  const int ld1 = (wid * 32 + 16) * 32;

  f32x4 acc[4][4];
#pragma unroll
  for (int i = 0; i < 4; ++i)
#pragma unroll
    for (int j = 0; j < 4; ++j) acc[i][j] = (f32x4){0.f, 0.f, 0.f, 0.f};

  GLDS(ag0,            &As[0][ld0]);
  GLDS(ag0 + 16 * 512, &As[0][ld1]);
  GLDS(bg0,            &Bs[0][ld0]);
  GLDS(bg0 + 16 * 512, &Bs[0][ld1]);
  __syncthreads();

  int cur = 0;
  for (int kt = 0; kt < 16; ++kt) {
    if (kt < 15) {                          // prefetch next K-tile (2-phase)
      const int o = (kt + 1) * 32;
      GLDS(ag0 + o,            &As[cur ^ 1][ld0]);
      GLDS(ag0 + o + 16 * 512, &As[cur ^ 1][ld1]);
      GLDS(bg0 + o,            &Bs[cur ^ 1][ld0]);
      GLDS(bg0 + o + 16 * 512, &Bs[cur ^ 1][ld1]);
    }
    bf16x8 a[4], b[4];
#pragma unroll
    for (int t = 0; t < 4; ++t) {
      a[t] = *(const bf16x8*)(&As[cur][(wm + t * 16 + (lane & 15)) * 32 + (lane >> 4) * 8]);
      b[t] = *(const bf16x8*)(&Bs[cur][(wn + t * 16 + (lane & 15)) * 32 + (lane >> 4) * 8]);
    }
#pragma unroll
    for (int mt = 0; mt < 4; ++mt)
#pragma unroll
      for (int nt = 0; nt < 4; ++nt)
        acc[mt][nt] = __builtin_amdgcn_mfma_f32_16x16x32_bf16(
            a[mt], b[nt], acc[mt][nt], 0, 0, 0);
    __syncthreads();
    cur ^= 1;
  }

  gemm_epilogue(acc, n0, m0, wm, wn, lane, bq, bk, bv, Qo, Ko, Vo);
}

// ---------- QKV GEMM fallback (round-1): fp32 A reg-staging ----------
__global__ __launch_bounds__(256) void qkv_gemm(
    const float* __restrict__ X, const unsigned short* __restrict__ Wc,
    const float* __restrict__ bq, const float* __restrict__ bk,
    const float* __restrict__ bv,
    unsigned short* __restrict__ Qo, unsigned short* __restrict__ Ko,
    unsigned short* __restrict__ Vo) {
  __shared__ __align__(16) unsigned short As[2][128 * 32];
  __shared__ __align__(16) unsigned short Bs[2][128 * 32];

  const int tid  = threadIdx.x;
  const int lane = tid & 63;
  const int wid  = tid >> 6;
  const int n0 = blockIdx.x * 128;
  const int m0 = blockIdx.y * 128;
  const int wm = (wid >> 1) * 64;
  const int wn = (wid & 1) * 64;

  const int ar = tid >> 1;
  const int ac = (tid & 1) * 16;
  const float* aptr = X + (size_t)(m0 + ar) * 512 + ac;
  const unsigned short* bg0 =
      Wc + (size_t)(n0 + wid * 32 + (lane >> 2)) * 512 + (lane & 3) * 8;
  const unsigned short* bg1 = bg0 + 16 * 512;

  f32x4 acc[4][4];
#pragma unroll
  for (int i = 0; i < 4; ++i)
#pragma unroll
    for (int j = 0; j < 4; ++j) acc[i][j] = (f32x4){0.f, 0.f, 0.f, 0.f};

  {
    float4 f0 = *(const float4*)(aptr + 0);
    float4 f1 = *(const float4*)(aptr + 4);
    float4 f2 = *(const float4*)(aptr + 8);
    float4 f3 = *(const float4*)(aptr + 12);
    __align__(16) unsigned short u[16];
    u[0]=f2bf(f0.x); u[1]=f2bf(f0.y); u[2]=f2bf(f0.z); u[3]=f2bf(f0.w);
    u[4]=f2bf(f1.x); u[5]=f2bf(f1.y); u[6]=f2bf(f1.z); u[7]=f2bf(f1.w);
    u[8]=f2bf(f2.x); u[9]=f2bf(f2.y); u[10]=f2bf(f2.z); u[11]=f2bf(f2.w);
    u[12]=f2bf(f3.x); u[13]=f2bf(f3.y); u[14]=f2bf(f3.z); u[15]=f2bf(f3.w);
    unsigned short* d = &As[0][ar * 32 + ac];
    *(bf16x8*)(d)     = *(const bf16x8*)(u);
    *(bf16x8*)(d + 8) = *(const bf16x8*)(u + 8);
    GLDS(bg0, &Bs[0][(wid * 32) * 32]);
    GLDS(bg1, &Bs[0][(wid * 32 + 16) * 32]);
  }
  __syncthreads();

  int cur = 0;
  for (int kt = 0; kt < 16; ++kt) {
    float4 f0, f1, f2, f3;
    if (kt < 15) {
      const float* ap = aptr + (kt + 1) * 32;
      f0 = *(const float4*)(ap + 0);
      f1 = *(const float4*)(ap + 4);
      f2 = *(const float4*)(ap + 8);
      f3 = *(const float4*)(ap + 12);
      GLDS(bg0 + (kt + 1) * 32, &Bs[cur ^ 1][(wid * 32) * 32]);
      GLDS(bg1 + (kt + 1) * 32, &Bs[cur ^ 1][(wid * 32 + 16) * 32]);
    }
    bf16x8 a[4], b[4];
#pragma unroll
    for (int t = 0; t < 4; ++t) {
      a[t] = *(const bf16x8*)(&As[cur][(wm + t * 16 + (lane & 15)) * 32 + (lane >> 4) * 8]);
      b[t] = *(const bf16x8*)(&Bs[cur][(wn + t * 16 + (lane & 15)) * 32 + (lane >> 4) * 8]);
    }
#pragma unroll
    for (int mt = 0; mt < 4; ++mt)
#pragma unroll
      for (int nt = 0; nt < 4; ++nt)
        acc[mt][nt] = __builtin_amdgcn_mfma_f32_16x16x32_bf16(
            a[mt], b[nt], acc[mt][nt], 0, 0, 0);
    if (kt < 15) {
      __align__(16) unsigned short u[16];
      u[0]=f2bf(f0.x); u[1]=f2bf(f0.y); u[2]=f2bf(f0.z); u[3]=f2bf(f0.w);
      u[4]=f2bf(f1.x); u[5]=f2bf(f1.y); u[6]=f2bf(f1.z); u[7]=f2bf(f1.w);
      u[8]=f2bf(f2.x); u[9]=f2bf(f2.y); u[10]=f2bf(f2.z); u[11]=f2bf(f2.w);
      u[12]=f2bf(f3.x); u[13]=f2bf(f3.y); u[14]=f2bf(f3.z); u[15]=f2bf(f3.w);
      unsigned short* d = &As[cur ^ 1][ar * 32 + ac];
      *(bf16x8*)(d)     = *(const bf16x8*)(u);
      *(bf16x8*)(d + 8) = *(const bf16x8*)(u + 8);
    }
    __syncthreads();
    cur ^= 1;
  }

  gemm_epilogue(acc, n0, m0, wm, wn, lane, bq, bk, bv, Qo, Ko, Vo);
}

// ---------- attention: 1 wave per (window, head) ----------
__global__ __launch_bounds__(64) void attn_win(
    const unsigned short* __restrict__ Qp, const unsigned short* __restrict__ Kp,
    const unsigned short* __restrict__ Vp, const float* __restrict__ Bb,
    float* __restrict__ out) {
  __shared__ __align__(16) unsigned short P[64 * 72];
  const int lane = threadIdx.x;
  const int win = blockIdx.x >> 3;
  const int h   = blockIdx.x & 7;
  const size_t base = (size_t)(win * 8 + h) * 4096;
  const unsigned short* q = Qp + base;
  const unsigned short* k = Kp + base;
  const unsigned short* v = Vp + base;   // V^T: [d][t]
  const int lr = lane & 15;
  const int hi = lane >> 4;

  bf16x8 qa[4][2], kb[4][2];
#pragma unroll
  for (int mt = 0; mt < 4; ++mt)
#pragma unroll
    for (int ks = 0; ks < 2; ++ks)
      qa[mt][ks] = *(const bf16x8*)(q + (size_t)(mt * 16 + lr) * 64 + ks * 32 + hi * 8);
#pragma unroll
  for (int nt = 0; nt < 4; ++nt)
#pragma unroll
    for (int ks = 0; ks < 2; ++ks)
      kb[nt][ks] = *(const bf16x8*)(k + (size_t)(nt * 16 + lr) * 64 + ks * 32 + hi * 8);

  f32x4 s[4][4];
#pragma unroll
  for (int mt = 0; mt < 4; ++mt)
#pragma unroll
    for (int nt = 0; nt < 4; ++nt) {
      s[mt][nt] = (f32x4){0.f, 0.f, 0.f, 0.f};
      s[mt][nt] = __builtin_amdgcn_mfma_f32_16x16x32_bf16(qa[mt][0], kb[nt][0], s[mt][nt], 0, 0, 0);
      s[mt][nt] = __builtin_amdgcn_mfma_f32_16x16x32_bf16(qa[mt][1], kb[nt][1], s[mt][nt], 0, 0, 0);
    }

#pragma unroll
  for (int mt = 0; mt < 4; ++mt)
#pragma unroll
    for (int nt = 0; nt < 4; ++nt)
#pragma unroll
      for (int rr = 0; rr < 4; ++rr)
        s[mt][nt][rr] += Bb[(mt * 16 + hi * 4 + rr) * 64 + nt * 16 + lr];

  float inv[4][4];
#pragma unroll
  for (int mt = 0; mt < 4; ++mt)
#pragma unroll
    for (int rr = 0; rr < 4; ++rr) {
      float m = fmaxf(fmaxf(s[mt][0][rr], s[mt][1][rr]),
                      fmaxf(s[mt][2][rr], s[mt][3][rr]));
      m = fmaxf(m, __shfl_xor(m, 1));
      m = fmaxf(m, __shfl_xor(m, 2));
      m = fmaxf(m, __shfl_xor(m, 4));
      m = fmaxf(m, __shfl_xor(m, 8));
      float sum = 0.f;
#pragma unroll
      for (int nt = 0; nt < 4; ++nt) {
        float e = __expf(s[mt][nt][rr] - m);
        s[mt][nt][rr] = e;
        sum += e;
      }
      sum += __shfl_xor(sum, 1);
      sum += __shfl_xor(sum, 2);
      sum += __shfl_xor(sum, 4);
      sum += __shfl_xor(sum, 8);
      inv[mt][rr] = 1.0f / sum;
    }

#pragma unroll
  for (int mt = 0; mt < 4; ++mt)
#pragma unroll
    for (int nt = 0; nt < 4; ++nt)
#pragma unroll
      for (int rr = 0; rr < 4; ++rr)
        P[(mt * 16 + hi * 4 + rr) * 72 + nt * 16 + lr] =
            f2bf(s[mt][nt][rr] * inv[mt][rr]);
  __syncthreads();

  bf16x8 pa[4][2], vb[4][2];
#pragma unroll
  for (int mt = 0; mt < 4; ++mt)
#pragma unroll
    for (int ks = 0; ks < 2; ++ks)
      pa[mt][ks] = *(const bf16x8*)(&P[(mt * 16 + lr) * 72 + ks * 32 + hi * 8]);
#pragma unroll
  for (int nt = 0; nt < 4; ++nt)
#pragma unroll
    for (int ks = 0; ks < 2; ++ks)
      vb[nt][ks] = *(const bf16x8*)(v + (size_t)(nt * 16 + lr) * 64 + ks * 32 + hi * 8);

  f32x4 o[4][4];
#pragma unroll
  for (int mt = 0; mt < 4; ++mt)
#pragma unroll
    for (int nt = 0; nt < 4; ++nt) {
      o[mt][nt] = (f32x4){0.f, 0.f, 0.f, 0.f};
      o[mt][nt] = __builtin_amdgcn_mfma_f32_16x16x32_bf16(pa[mt][0], vb[nt][0], o[mt][nt], 0, 0, 0);
      o[mt][nt] = __builtin_amdgcn_mfma_f32_16x16x32_bf16(pa[mt][1], vb[nt][1], o[mt][nt], 0, 0, 0);
    }

  float* op = out + (size_t)win * 32768 + h * 64;
#pragma unroll
  for (int mt = 0; mt < 4; ++mt)
#pragma unroll
    for (int nt = 0; nt < 4; ++nt)
#pragma unroll
      for (int rr = 0; rr < 4; ++rr)
        op[(size_t)(mt * 16 + hi * 4 + rr) * 512 + nt * 16 + lr] = o[mt][nt][rr];
}

extern "C" void kernel_launch(void* const* d_in, const int* in_sizes, int n_in,
                              void* d_out, int out_size, void* d_ws, size_t ws_size,
                              hipStream_t stream) {
  const float* x     = (const float*)d_in[0];
  const float* Wq    = (const float*)d_in[1];
  const float* bq    = (const float*)d_in[2];
  const float* Wk    = (const float*)d_in[3];
  const float* bk    = (const float*)d_in[4];
  const float* Wv    = (const float*)d_in[5];
  const float* bv    = (const float*)d_in[6];
  const float* Bbias = (const float*)d_in[7];
  float* out = (float*)d_out;

  if (ws_size >= ((size_t)132 << 20)) {
    // fast: Wc@0 | Xb@2MiB | Q@36MiB | K@68MiB | V^T@100MiB
    unsigned short* Wc = (unsigned short*)d_ws;
    unsigned short* Xb = (unsigned short*)((char*)d_ws + ((size_t)2 << 20));
    unsigned short* Q  = (unsigned short*)((char*)d_ws + ((size_t)36 << 20));
    unsigned short* K  = (unsigned short*)((char*)d_ws + ((size_t)68 << 20));
    unsigned short* V  = (unsigned short*)((char*)d_ws + ((size_t)100 << 20));
    prep_convert<<<dim3(8576), dim3(256), 0, stream>>>(x, Wq, Wk, Wv, Xb, Wc);
    qkv_gemm_bf16<<<dim3(3072), dim3(256), 0, stream>>>(Xb, Wc, bq, bk, bv, Q, K, V);
    attn_win<<<dim3(4096), dim3(64), 0, stream>>>(Q, K, V, Bbias, out);
  } else {
    // fallback (round-1 proven): Wc@0 | Q@2MiB | K@34MiB | V^T@66MiB
    unsigned short* Wc = (unsigned short*)d_ws;
    unsigned short* Q  = (unsigned short*)((char*)d_ws + ((size_t)2 << 20));
    unsigned short* K  = (unsigned short*)((char*)d_ws + ((size_t)34 << 20));
    unsigned short* V  = (unsigned short*)((char*)d_ws + ((size_t)66 << 20));
    prep_weights<<<dim3(768), dim3(256), 0, stream>>>(Wq, Wk, Wv, Wc);
    qkv_gemm<<<dim3(12, 256), dim3(256), 0, stream>>>(x, Wc, bq, bk, bv, Q, K, V);
    attn_win<<<dim3(4096), dim3(64), 0, stream>>>(Q, K, V, Bbias, out);
  }
}

// Round 3
// 119.969 us; speedup vs baseline: 1.3196x; 1.0988x over previous
//
#include <hip/hip_runtime.h>
#include <hip/hip_bf16.h>

// B=8, C=512, H=W=64, NH=8, HD=64, WIN=64, NW=64.
// Token matrix = x viewed as [32768][512] fp32 (raw reshape).
//   phase 0: convert X -> bf16, W{q,k,v} -> Wcat bf16 [1536][512]
//   phase 1: QKV GEMM M=32768 K=512 N=1536 — 256x256 tile, BK=64, 8-phase
//            schedule (T2 st_16x32 swizzle + T3/T4 counted vmcnt + T5 setprio)
//   phase 2: per (window,head): S=Q@K^T(+bias), softmax, P@V
// ws: Wc@0 | Xb@2MiB | Q@36MiB | K@68MiB | V^T@100MiB (132MiB; proven fits).

typedef __attribute__((ext_vector_type(8))) short bf16x8;
typedef __attribute__((ext_vector_type(4))) float f32x4;

#define GLDS(gp, lp) __builtin_amdgcn_global_load_lds( \
    (const __attribute__((address_space(1))) unsigned int*)(gp), \
    (__attribute__((address_space(3))) unsigned int*)(lp), 16, 0, 0)

__device__ __forceinline__ unsigned short f2bf(float f) {
  union { float f; unsigned int u; } v; v.f = f;
  unsigned int r = v.u + 0x7fffu + ((v.u >> 16) & 1u);  // RNE
  return (unsigned short)(r >> 16);
}

// ---------- prep: X fp32->bf16 and W{q,k,v} -> Wcat bf16 ----------
__global__ __launch_bounds__(256) void prep_convert(
    const float* __restrict__ X, const float* __restrict__ Wq,
    const float* __restrict__ Wk, const float* __restrict__ Wv,
    unsigned short* __restrict__ Xb, unsigned short* __restrict__ Wc) {
  const unsigned int i = blockIdx.x * 256 + threadIdx.x;
  const float* src;
  unsigned short* dst;
  if (i < 2097152u) {                       // X: 16.7M floats, 8 per thread
    src = X + (size_t)i * 8;
    dst = Xb + (size_t)i * 8;
  } else {                                  // Wcat: [1536][512]
    const unsigned int j = i - 2097152u;    // < 98304
    const unsigned int e = j * 8;
    const unsigned int n = e >> 9, kk = e & 511;
    src = ((n < 512) ? Wq : (n < 1024 ? Wk : Wv)) + (size_t)(n & 511) * 512 + kk;
    dst = Wc + (size_t)n * 512 + kk;
  }
  float4 f0 = *(const float4*)(src);
  float4 f1 = *(const float4*)(src + 4);
  __align__(16) unsigned short u[8];
  u[0] = f2bf(f0.x); u[1] = f2bf(f0.y); u[2] = f2bf(f0.z); u[3] = f2bf(f0.w);
  u[4] = f2bf(f1.x); u[5] = f2bf(f1.y); u[6] = f2bf(f1.z); u[7] = f2bf(f1.w);
  *(bf16x8*)(dst) = *(const bf16x8*)(u);
}

// ---------- QKV GEMM: 256x256 tile, BK=64, 8 waves, 8-phase schedule ----------
// LDS 128KiB: A [0,64K): 2 buf x 2 half x [128 rows][64 cols] bf16 (subtiled
// 1KiB = 16x32, st_16x32 swizzle); B same at [64K,128K).
// Staging lead 1.5 K-tiles: P1: A1(t+1); P3: B0(t+2); P4: B1(t+2)+A0(t+2);
// one counted vmcnt(6) per K-tile at the boundary (never 0 mid-loop).
__global__ __launch_bounds__(512, 2) void qkv_gemm_256(
    const unsigned short* __restrict__ Xb, const unsigned short* __restrict__ Wc,
    const float* __restrict__ bq, const float* __restrict__ bk,
    const float* __restrict__ bv,
    unsigned short* __restrict__ Qo, unsigned short* __restrict__ Ko,
    unsigned short* __restrict__ Vo) {
  __shared__ __align__(16) char LDS[131072];

  const int tid  = threadIdx.x;
  const int lane = tid & 63;
  const int wid  = tid >> 6;
  const int wm = wid >> 2, wn = wid & 3;

  // XCD-chunked swizzle: 768 = 8 x 96 works; n-tiles fastest within a chunk.
  const int work = (int)(blockIdx.x & 7) * 96 + (int)(blockIdx.x >> 3);
  const int bx = work % 6, by = work / 6;
  const int n0 = bx * 256, m0 = by * 256;

  // --- staging addressing (linear LDS dest; inverse-swizzled global source) ---
  // subtile = j*8+wid (1KiB each); lane covers row lane>>2, 16B chunk lane&3,
  // source col chunk XOR'd for lanes>=32 (involution of the read-side swizzle).
  const int lcol  = ((lane & 3) * 8) ^ ((lane >= 32) ? 16 : 0);   // elements
  const int arow0 = (wid >> 1) * 16 + (lane >> 2);                // j=0 row
  const int acol0 = (wid & 1) * 32 + lcol;                        // j=0 col

#define STAGE_A(half, tt) do { \
    const unsigned short* g = Xb + (size_t)(m0 + (half) * 128 + arow0) * 512 + (tt) * 64 + acol0; \
    char* l = LDS + ((tt) & 1) * 32768 + (half) * 16384 + wid * 1024; \
    GLDS(g, l); \
    GLDS(g + 64 * 512, l + 8192); \
  } while (0)

#define STAGE_B(half, tt) do { \
    const unsigned short* g = Wc + (size_t)(n0 + (half) * 128 + arow0) * 512 + (tt) * 64 + acol0; \
    char* l = LDS + 65536 + ((tt) & 1) * 32768 + (half) * 16384 + wid * 1024; \
    GLDS(g, l); \
    GLDS(g + 64 * 512, l + 8192); \
  } while (0)

  // --- fragment-read addressing (swizzled) ---
  // logical: off = F*2048 + ks*1024 + (lane&15)*64 + (lane>>4)*16,
  // phys = off ^ ((lane&8) ? 32 : 0)   [st_16x32: bit9 of subtile-off = row&8]
  const int sloff = (((lane & 15) * 64) + ((lane >> 4) * 16)) ^ ((lane & 8) ? 32 : 0);
  char* const Ab = LDS + wm * 16384 + sloff;
  char* const Bb2 = LDS + 65536 + (wn >> 1) * 16384 + sloff;
  const int bfr = (wn & 1) * 4;   // B frag index base within half

  f32x4 acc[8][4];
#pragma unroll
  for (int i = 0; i < 8; ++i)
#pragma unroll
    for (int j = 0; j < 4; ++j) acc[i][j] = (f32x4){0.f, 0.f, 0.f, 0.f};

  bf16x8 a[4][2], b0[2][2], b1[2][2];

#define LDA(mh, bo) do { \
    _Pragma("unroll") for (int mi = 0; mi < 4; ++mi) \
    _Pragma("unroll") for (int ks = 0; ks < 2; ++ks) \
      a[mi][ks] = *(const bf16x8*)(Ab + (bo) + ((mh) * 4 + mi) * 2048 + ks * 1024); \
  } while (0)

#define LDB(dst, nh, bo) do { \
    _Pragma("unroll") for (int ni = 0; ni < 2; ++ni) \
    _Pragma("unroll") for (int ks = 0; ks < 2; ++ks) \
      dst[ni][ks] = *(const bf16x8*)(Bb2 + (bo) + (bfr + (nh) * 2 + ni) * 2048 + ks * 1024); \
  } while (0)

#define MM(mh, nh, bb) do { \
    _Pragma("unroll") for (int mi = 0; mi < 4; ++mi) \
    _Pragma("unroll") for (int ni = 0; ni < 2; ++ni) \
    _Pragma("unroll") for (int ks = 0; ks < 2; ++ks) \
      acc[(mh) * 4 + mi][(nh) * 2 + ni] = __builtin_amdgcn_mfma_f32_16x16x32_bf16( \
          a[mi][ks], bb[ni][ks], acc[(mh) * 4 + mi][(nh) * 2 + ni], 0, 0, 0); \
  } while (0)

#define PHASE_PRE()  __builtin_amdgcn_s_barrier(); \
                     asm volatile("s_waitcnt lgkmcnt(0)" ::: "memory"); \
                     __builtin_amdgcn_sched_barrier(0); \
                     __builtin_amdgcn_s_setprio(1)
#define PHASE_POST() __builtin_amdgcn_s_setprio(0); \
                     __builtin_amdgcn_s_barrier()

  // prologue: tile0 fully + tile1's B0,B1,A0 (A1(1) comes at P1 of t=0)
  STAGE_A(0, 0); STAGE_A(1, 0); STAGE_B(0, 0); STAGE_B(1, 0);
  STAGE_B(0, 1); STAGE_B(1, 1); STAGE_A(0, 1);
  asm volatile("s_waitcnt vmcnt(6)" ::: "memory");   // retire tile0's 8 loads
  __builtin_amdgcn_s_barrier();

  for (int t = 0; t < 8; ++t) {
    const int bo = (t & 1) * 32768;
    // ---- P1: quadrant (0,0) ----
    LDA(0, bo); LDB(b0, 0, bo);
    if (t + 1 < 8) STAGE_A(1, t + 1);
    PHASE_PRE();
    MM(0, 0, b0);
    PHASE_POST();
    // ---- P2: quadrant (0,1) ----
    LDB(b1, 1, bo);
    PHASE_PRE();
    MM(0, 1, b1);
    PHASE_POST();
    // ---- P3: quadrant (1,1) ----
    LDA(1, bo);
    if (t + 2 < 8) STAGE_B(0, t + 2);
    PHASE_PRE();
    MM(1, 1, b1);
    PHASE_POST();
    // ---- P4: quadrant (1,0) ----
    if (t + 2 < 8) { STAGE_B(1, t + 2); STAGE_A(0, t + 2); }
    __builtin_amdgcn_s_barrier();
    __builtin_amdgcn_s_setprio(1);
    MM(1, 0, b0);
    __builtin_amdgcn_s_setprio(0);
    if (t + 2 < 8)      asm volatile("s_waitcnt vmcnt(6)" ::: "memory");
    else if (t + 1 < 8) asm volatile("s_waitcnt vmcnt(0)" ::: "memory");
    __builtin_amdgcn_s_barrier();
  }

  // ---- epilogue: +bias, Q scaled 1/8; Q,K -> [win][h][t][d], V -> [d][t] ----
  const int p = n0 >> 9;                    // 0:Q 1:K 2:V (256-tile never spans)
  const float* bias = (p == 0) ? bq : (p == 1) ? bk : bv;
  const float qs = (p == 0) ? 0.125f : 1.0f;
  const int hi = lane >> 4, lr = lane & 15;
#pragma unroll
  for (int F = 0; F < 8; ++F) {
    const int r0 = m0 + wm * 128 + F * 16;  // 16-row block within one window
    const int win = r0 >> 6;
    const int t0 = (r0 & 63) + hi * 4;
#pragma unroll
    for (int ni = 0; ni < 4; ++ni) {
      const int ncol = (n0 & 511) + wn * 64 + ni * 16 + lr;
      const float bsv = bias[ncol];
      const int h = ncol >> 6, dch = ncol & 63;
      const size_t hb = (size_t)(win * 8 + h) * 4096;
      if (p < 2) {
        unsigned short* dst = ((p == 0) ? Qo : Ko) + hb;
#pragma unroll
        for (int rr = 0; rr < 4; ++rr)
          dst[(size_t)(t0 + rr) * 64 + dch] = f2bf((acc[F][ni][rr] + bsv) * qs);
      } else {
        ushort4 pk;  // 4 consecutive t, fixed d -> 8B store into V^T [d][t]
        pk.x = f2bf(acc[F][ni][0] + bsv);
        pk.y = f2bf(acc[F][ni][1] + bsv);
        pk.z = f2bf(acc[F][ni][2] + bsv);
        pk.w = f2bf(acc[F][ni][3] + bsv);
        *(ushort4*)(Vo + hb + (size_t)dch * 64 + t0) = pk;
      }
    }
  }
#undef STAGE_A
#undef STAGE_B
#undef LDA
#undef LDB
#undef MM
#undef PHASE_PRE
#undef PHASE_POST
}

// ---------- attention: 1 wave per (window, head) ----------
__global__ __launch_bounds__(64) void attn_win(
    const unsigned short* __restrict__ Qp, const unsigned short* __restrict__ Kp,
    const unsigned short* __restrict__ Vp, const float* __restrict__ Bb,
    float* __restrict__ out) {
  __shared__ __align__(16) unsigned short P[64 * 72];
  const int lane = threadIdx.x;
  const int win = blockIdx.x >> 3;
  const int h   = blockIdx.x & 7;
  const size_t base = (size_t)(win * 8 + h) * 4096;
  const unsigned short* q = Qp + base;
  const unsigned short* k = Kp + base;
  const unsigned short* v = Vp + base;   // V^T: [d][t]
  const int lr = lane & 15;
  const int hi = lane >> 4;

  bf16x8 qa[4][2], kb[4][2];
#pragma unroll
  for (int mt = 0; mt < 4; ++mt)
#pragma unroll
    for (int ks = 0; ks < 2; ++ks)
      qa[mt][ks] = *(const bf16x8*)(q + (size_t)(mt * 16 + lr) * 64 + ks * 32 + hi * 8);
#pragma unroll
  for (int nt = 0; nt < 4; ++nt)
#pragma unroll
    for (int ks = 0; ks < 2; ++ks)
      kb[nt][ks] = *(const bf16x8*)(k + (size_t)(nt * 16 + lr) * 64 + ks * 32 + hi * 8);

  f32x4 s[4][4];
#pragma unroll
  for (int mt = 0; mt < 4; ++mt)
#pragma unroll
    for (int nt = 0; nt < 4; ++nt) {
      s[mt][nt] = (f32x4){0.f, 0.f, 0.f, 0.f};
      s[mt][nt] = __builtin_amdgcn_mfma_f32_16x16x32_bf16(qa[mt][0], kb[nt][0], s[mt][nt], 0, 0, 0);
      s[mt][nt] = __builtin_amdgcn_mfma_f32_16x16x32_bf16(qa[mt][1], kb[nt][1], s[mt][nt], 0, 0, 0);
    }

#pragma unroll
  for (int mt = 0; mt < 4; ++mt)
#pragma unroll
    for (int nt = 0; nt < 4; ++nt)
#pragma unroll
      for (int rr = 0; rr < 4; ++rr)
        s[mt][nt][rr] += Bb[(mt * 16 + hi * 4 + rr) * 64 + nt * 16 + lr];

  float inv[4][4];
#pragma unroll
  for (int mt = 0; mt < 4; ++mt)
#pragma unroll
    for (int rr = 0; rr < 4; ++rr) {
      float m = fmaxf(fmaxf(s[mt][0][rr], s[mt][1][rr]),
                      fmaxf(s[mt][2][rr], s[mt][3][rr]));
      m = fmaxf(m, __shfl_xor(m, 1));
      m = fmaxf(m, __shfl_xor(m, 2));
      m = fmaxf(m, __shfl_xor(m, 4));
      m = fmaxf(m, __shfl_xor(m, 8));
      float sum = 0.f;
#pragma unroll
      for (int nt = 0; nt < 4; ++nt) {
        float e = __expf(s[mt][nt][rr] - m);
        s[mt][nt][rr] = e;
        sum += e;
      }
      sum += __shfl_xor(sum, 1);
      sum += __shfl_xor(sum, 2);
      sum += __shfl_xor(sum, 4);
      sum += __shfl_xor(sum, 8);
      inv[mt][rr] = 1.0f / sum;
    }

#pragma unroll
  for (int mt = 0; mt < 4; ++mt)
#pragma unroll
    for (int nt = 0; nt < 4; ++nt)
#pragma unroll
      for (int rr = 0; rr < 4; ++rr)
        P[(mt * 16 + hi * 4 + rr) * 72 + nt * 16 + lr] =
            f2bf(s[mt][nt][rr] * inv[mt][rr]);
  __syncthreads();

  bf16x8 pa[4][2], vb[4][2];
#pragma unroll
  for (int mt = 0; mt < 4; ++mt)
#pragma unroll
    for (int ks = 0; ks < 2; ++ks)
      pa[mt][ks] = *(const bf16x8*)(&P[(mt * 16 + lr) * 72 + ks * 32 + hi * 8]);
#pragma unroll
  for (int nt = 0; nt < 4; ++nt)
#pragma unroll
    for (int ks = 0; ks < 2; ++ks)
      vb[nt][ks] = *(const bf16x8*)(v + (size_t)(nt * 16 + lr) * 64 + ks * 32 + hi * 8);

  f32x4 o[4][4];
#pragma unroll
  for (int mt = 0; mt < 4; ++mt)
#pragma unroll
    for (int nt = 0; nt < 4; ++nt) {
      o[mt][nt] = (f32x4){0.f, 0.f, 0.f, 0.f};
      o[mt][nt] = __builtin_amdgcn_mfma_f32_16x16x32_bf16(pa[mt][0], vb[nt][0], o[mt][nt], 0, 0, 0);
      o[mt][nt] = __builtin_amdgcn_mfma_f32_16x16x32_bf16(pa[mt][1], vb[nt][1], o[mt][nt], 0, 0, 0);
    }

  float* op = out + (size_t)win * 32768 + h * 64;
#pragma unroll
  for (int mt = 0; mt < 4; ++mt)
#pragma unroll
    for (int nt = 0; nt < 4; ++nt)
#pragma unroll
      for (int rr = 0; rr < 4; ++rr)
        op[(size_t)(mt * 16 + hi * 4 + rr) * 512 + nt * 16 + lr] = o[mt][nt][rr];
}

extern "C" void kernel_launch(void* const* d_in, const int* in_sizes, int n_in,
                              void* d_out, int out_size, void* d_ws, size_t ws_size,
                              hipStream_t stream) {
  const float* x     = (const float*)d_in[0];
  const float* Wq    = (const float*)d_in[1];
  const float* bq    = (const float*)d_in[2];
  const float* Wk    = (const float*)d_in[3];
  const float* bk    = (const float*)d_in[4];
  const float* Wv    = (const float*)d_in[5];
  const float* bv    = (const float*)d_in[6];
  const float* Bbias = (const float*)d_in[7];
  float* out = (float*)d_out;

  // ws: Wc@0 | Xb@2MiB | Q@36MiB | K@68MiB | V^T@100MiB
  unsigned short* Wc = (unsigned short*)d_ws;
  unsigned short* Xb = (unsigned short*)((char*)d_ws + ((size_t)2 << 20));
  unsigned short* Q  = (unsigned short*)((char*)d_ws + ((size_t)36 << 20));
  unsigned short* K  = (unsigned short*)((char*)d_ws + ((size_t)68 << 20));
  unsigned short* V  = (unsigned short*)((char*)d_ws + ((size_t)100 << 20));

  prep_convert<<<dim3(8576), dim3(256), 0, stream>>>(x, Wq, Wk, Wv, Xb, Wc);
  qkv_gemm_256<<<dim3(768), dim3(512), 0, stream>>>(Xb, Wc, bq, bk, bv, Q, K, V);
  attn_win<<<dim3(4096), dim3(64), 0, stream>>>(Q, K, V, Bbias, out);
}

// Round 4
// 114.258 us; speedup vs baseline: 1.3856x; 1.0500x over previous
//
#include <hip/hip_runtime.h>
#include <hip/hip_bf16.h>

// B=8, C=512, H=W=64, NH=8, HD=64, WIN=64, NW=64.
// Token matrix = x viewed as [32768][512] fp32 (raw reshape).
//   phase 0: convert X -> bf16, W{q,k,v} -> Wcat bf16 [1536][512]
//   phase 1: QKV GEMM M=32768 K=512 N=1536 — 256x256 tile, BK=64, 8-phase
//            schedule (T2 swizzle + T3/T4 counted vmcnt + T5 setprio),
//            LDS-staged coalesced epilogue (16B stores, chunk-XOR scratch)
//   phase 2: per (window,head): S=Q@K^T(+bias), softmax, P@V
// ws: Wc@0 | Xb@2MiB | Q@36MiB | K@68MiB | V^T@100MiB (132MiB; fits).

typedef __attribute__((ext_vector_type(8))) short bf16x8;
typedef __attribute__((ext_vector_type(4))) float f32x4;

#define GLDS(gp, lp) __builtin_amdgcn_global_load_lds( \
    (const __attribute__((address_space(1))) unsigned int*)(gp), \
    (__attribute__((address_space(3))) unsigned int*)(lp), 16, 0, 0)

__device__ __forceinline__ unsigned short f2bf(float f) {
  union { float f; unsigned int u; } v; v.f = f;
  unsigned int r = v.u + 0x7fffu + ((v.u >> 16) & 1u);  // RNE
  return (unsigned short)(r >> 16);
}

// ---------- prep: X fp32->bf16 and W{q,k,v} -> Wcat bf16 ----------
__global__ __launch_bounds__(256) void prep_convert(
    const float* __restrict__ X, const float* __restrict__ Wq,
    const float* __restrict__ Wk, const float* __restrict__ Wv,
    unsigned short* __restrict__ Xb, unsigned short* __restrict__ Wc) {
  const unsigned int i = blockIdx.x * 256 + threadIdx.x;
  const float* src;
  unsigned short* dst;
  if (i < 2097152u) {                       // X: 16.7M floats, 8 per thread
    src = X + (size_t)i * 8;
    dst = Xb + (size_t)i * 8;
  } else {                                  // Wcat: [1536][512]
    const unsigned int j = i - 2097152u;    // < 98304
    const unsigned int e = j * 8;
    const unsigned int n = e >> 9, kk = e & 511;
    src = ((n < 512) ? Wq : (n < 1024 ? Wk : Wv)) + (size_t)(n & 511) * 512 + kk;
    dst = Wc + (size_t)n * 512 + kk;
  }
  float4 f0 = *(const float4*)(src);
  float4 f1 = *(const float4*)(src + 4);
  __align__(16) unsigned short u[8];
  u[0] = f2bf(f0.x); u[1] = f2bf(f0.y); u[2] = f2bf(f0.z); u[3] = f2bf(f0.w);
  u[4] = f2bf(f1.x); u[5] = f2bf(f1.y); u[6] = f2bf(f1.z); u[7] = f2bf(f1.w);
  *(bf16x8*)(dst) = *(const bf16x8*)(u);
}

// ---------- QKV GEMM: 256x256 tile, BK=64, 8 waves, 8-phase schedule ----------
// K-loop identical to round 3 (validated). New: coalesced epilogue via LDS.
__global__ __launch_bounds__(512, 2) void qkv_gemm_256(
    const unsigned short* __restrict__ Xb, const unsigned short* __restrict__ Wc,
    const float* __restrict__ bq, const float* __restrict__ bk,
    const float* __restrict__ bv,
    unsigned short* __restrict__ Qo, unsigned short* __restrict__ Ko,
    unsigned short* __restrict__ Vo) {
  __shared__ __align__(16) char LDS[131072];

  const int tid  = threadIdx.x;
  const int lane = tid & 63;
  const int wid  = tid >> 6;
  const int wm = wid >> 2, wn = wid & 3;

  // XCD-chunked swizzle: 768 = 8 x 96 works; n-tiles fastest within a chunk.
  const int work = (int)(blockIdx.x & 7) * 96 + (int)(blockIdx.x >> 3);
  const int bx = work % 6, by = work / 6;
  const int n0 = bx * 256, m0 = by * 256;

  // --- staging addressing (linear LDS dest; inverse-swizzled global source) ---
  const int lcol  = ((lane & 3) * 8) ^ ((lane >= 32) ? 16 : 0);   // elements
  const int arow0 = (wid >> 1) * 16 + (lane >> 2);                // j=0 row
  const int acol0 = (wid & 1) * 32 + lcol;                        // j=0 col

#define STAGE_A(half, tt) do { \
    const unsigned short* g = Xb + (size_t)(m0 + (half) * 128 + arow0) * 512 + (tt) * 64 + acol0; \
    char* l = LDS + ((tt) & 1) * 32768 + (half) * 16384 + wid * 1024; \
    GLDS(g, l); \
    GLDS(g + 64 * 512, l + 8192); \
  } while (0)

#define STAGE_B(half, tt) do { \
    const unsigned short* g = Wc + (size_t)(n0 + (half) * 128 + arow0) * 512 + (tt) * 64 + acol0; \
    char* l = LDS + 65536 + ((tt) & 1) * 32768 + (half) * 16384 + wid * 1024; \
    GLDS(g, l); \
    GLDS(g + 64 * 512, l + 8192); \
  } while (0)

  // --- fragment-read addressing (swizzled) ---
  const int sloff = (((lane & 15) * 64) + ((lane >> 4) * 16)) ^ ((lane & 8) ? 32 : 0);
  char* const Ab = LDS + wm * 16384 + sloff;
  char* const Bb2 = LDS + 65536 + (wn >> 1) * 16384 + sloff;
  const int bfr = (wn & 1) * 4;   // B frag index base within half

  f32x4 acc[8][4];
#pragma unroll
  for (int i = 0; i < 8; ++i)
#pragma unroll
    for (int j = 0; j < 4; ++j) acc[i][j] = (f32x4){0.f, 0.f, 0.f, 0.f};

  bf16x8 a[4][2], b0[2][2], b1[2][2];

#define LDA(mh, bo) do { \
    _Pragma("unroll") for (int mi = 0; mi < 4; ++mi) \
    _Pragma("unroll") for (int ks = 0; ks < 2; ++ks) \
      a[mi][ks] = *(const bf16x8*)(Ab + (bo) + ((mh) * 4 + mi) * 2048 + ks * 1024); \
  } while (0)

#define LDB(dst, nh, bo) do { \
    _Pragma("unroll") for (int ni = 0; ni < 2; ++ni) \
    _Pragma("unroll") for (int ks = 0; ks < 2; ++ks) \
      dst[ni][ks] = *(const bf16x8*)(Bb2 + (bo) + (bfr + (nh) * 2 + ni) * 2048 + ks * 1024); \
  } while (0)

#define MM(mh, nh, bb) do { \
    _Pragma("unroll") for (int mi = 0; mi < 4; ++mi) \
    _Pragma("unroll") for (int ni = 0; ni < 2; ++ni) \
    _Pragma("unroll") for (int ks = 0; ks < 2; ++ks) \
      acc[(mh) * 4 + mi][(nh) * 2 + ni] = __builtin_amdgcn_mfma_f32_16x16x32_bf16( \
          a[mi][ks], bb[ni][ks], acc[(mh) * 4 + mi][(nh) * 2 + ni], 0, 0, 0); \
  } while (0)

#define PHASE_PRE()  __builtin_amdgcn_s_barrier(); \
                     asm volatile("s_waitcnt lgkmcnt(0)" ::: "memory"); \
                     __builtin_amdgcn_sched_barrier(0); \
                     __builtin_amdgcn_s_setprio(1)
#define PHASE_POST() __builtin_amdgcn_s_setprio(0); \
                     __builtin_amdgcn_s_barrier()

  // prologue: tile0 fully + tile1's B0,B1,A0 (A1(1) comes at P1 of t=0)
  STAGE_A(0, 0); STAGE_A(1, 0); STAGE_B(0, 0); STAGE_B(1, 0);
  STAGE_B(0, 1); STAGE_B(1, 1); STAGE_A(0, 1);
  asm volatile("s_waitcnt vmcnt(6)" ::: "memory");   // retire tile0's 8 loads
  __builtin_amdgcn_s_barrier();

  for (int t = 0; t < 8; ++t) {
    const int bo = (t & 1) * 32768;
    // ---- P1: quadrant (0,0) ----
    LDA(0, bo); LDB(b0, 0, bo);
    if (t + 1 < 8) STAGE_A(1, t + 1);
    PHASE_PRE();
    MM(0, 0, b0);
    PHASE_POST();
    // ---- P2: quadrant (0,1) ----
    LDB(b1, 1, bo);
    PHASE_PRE();
    MM(0, 1, b1);
    PHASE_POST();
    // ---- P3: quadrant (1,1) ----
    LDA(1, bo);
    if (t + 2 < 8) STAGE_B(0, t + 2);
    PHASE_PRE();
    MM(1, 1, b1);
    PHASE_POST();
    // ---- P4: quadrant (1,0) ----
    if (t + 2 < 8) { STAGE_B(1, t + 2); STAGE_A(0, t + 2); }
    __builtin_amdgcn_s_barrier();
    __builtin_amdgcn_s_setprio(1);
    MM(1, 0, b0);
    __builtin_amdgcn_s_setprio(0);
    if (t + 2 < 8)      asm volatile("s_waitcnt vmcnt(6)" ::: "memory");
    else if (t + 1 < 8) asm volatile("s_waitcnt vmcnt(0)" ::: "memory");
    __builtin_amdgcn_s_barrier();
  }

  // ---- epilogue: LDS-staged, coalesced 16B stores ----
  // Wave's 128x64 output = 2 windows x 1 head (64-ch span = one head).
  // Per window: stage 64x64 bf16 tile in private 8KiB scratch with chunk-XOR
  // (phys = r*64 + (d ^ ((r&7)<<3)) shorts): writes 2-way (free), b128 row
  // reads conflict-free, then 8 fully-coalesced 1KiB global store instrs.
  {
    const int p = n0 >> 9;                  // 0:Q 1:K 2:V (256-tile never spans)
    const float* bias = (p == 0) ? bq : (p == 1) ? bk : bv;
    const float qs = (p == 0) ? 0.125f : 1.0f;
    const int hi = lane >> 4, lr = lane & 15;
    const int h = ((n0 & 511) + wn * 64) >> 6;
    char* const scr = LDS + wid * 8192;
    float bsv[4];
#pragma unroll
    for (int ni = 0; ni < 4; ++ni)
      bsv[ni] = bias[(n0 & 511) + wn * 64 + ni * 16 + lr];

#pragma unroll
    for (int wh = 0; wh < 2; ++wh) {
      asm volatile("s_waitcnt lgkmcnt(0)" ::: "memory");  // WAR vs prev reads
      __builtin_amdgcn_sched_barrier(0);
      if (p < 2) {
        // T[t][d]: thread writes (t = f*16+hi*4+rr, d = ni*16+lr)
#pragma unroll
        for (int f = 0; f < 4; ++f)
#pragma unroll
          for (int ni = 0; ni < 4; ++ni) {
            const int d = ni * 16 + lr;
#pragma unroll
            for (int rr = 0; rr < 4; ++rr) {
              const int t = f * 16 + hi * 4 + rr;
              const int off = t * 64 + (d ^ ((t & 7) << 3));
              *(unsigned short*)(scr + off * 2) =
                  f2bf((acc[wh * 4 + f][ni][rr] + bsv[ni]) * qs);
            }
          }
      } else {
        // T'[d][t]: thread packs 4 consecutive t (rr) at fixed d -> b64
#pragma unroll
        for (int f = 0; f < 4; ++f)
#pragma unroll
          for (int ni = 0; ni < 4; ++ni) {
            const int d = ni * 16 + lr;
            const int t0 = f * 16 + hi * 4;
            ushort4 pk;
            pk.x = f2bf(acc[wh * 4 + f][ni][0] + bsv[ni]);
            pk.y = f2bf(acc[wh * 4 + f][ni][1] + bsv[ni]);
            pk.z = f2bf(acc[wh * 4 + f][ni][2] + bsv[ni]);
            pk.w = f2bf(acc[wh * 4 + f][ni][3] + bsv[ni]);
            const int off = d * 64 + (t0 ^ ((d & 7) << 3));
            *(ushort4*)(scr + off * 2) = pk;
          }
      }
      asm volatile("s_waitcnt lgkmcnt(0)" ::: "memory");  // writes -> readable
      __builtin_amdgcn_sched_barrier(0);
      const int win = (m0 + wm * 128 + wh * 64) >> 6;
      unsigned short* dst =
          ((p == 0) ? Qo : (p == 1) ? Ko : Vo) + (size_t)(win * 8 + h) * 4096;
#pragma unroll
      for (int i = 0; i < 8; ++i) {
        const int r = i * 8 + (lane >> 3);
        const int c = lane & 7;
        const int off = r * 64 + ((c ^ (r & 7)) * 8);
        bf16x8 row = *(const bf16x8*)(scr + off * 2);   // ds_read_b128
        *(bf16x8*)(dst + r * 64 + c * 8) = row;         // coalesced 16B store
      }
    }
  }
#undef STAGE_A
#undef STAGE_B
#undef LDA
#undef LDB
#undef MM
#undef PHASE_PRE
#undef PHASE_POST
}

// ---------- attention: 1 wave per (window, head) ----------
__global__ __launch_bounds__(64) void attn_win(
    const unsigned short* __restrict__ Qp, const unsigned short* __restrict__ Kp,
    const unsigned short* __restrict__ Vp, const float* __restrict__ Bb,
    float* __restrict__ out) {
  __shared__ __align__(16) unsigned short P[64 * 72];
  const int lane = threadIdx.x;
  const int win = blockIdx.x >> 3;
  const int h   = blockIdx.x & 7;
  const size_t base = (size_t)(win * 8 + h) * 4096;
  const unsigned short* q = Qp + base;
  const unsigned short* k = Kp + base;
  const unsigned short* v = Vp + base;   // V^T: [d][t]
  const int lr = lane & 15;
  const int hi = lane >> 4;

  bf16x8 qa[4][2], kb[4][2];
#pragma unroll
  for (int mt = 0; mt < 4; ++mt)
#pragma unroll
    for (int ks = 0; ks < 2; ++ks)
      qa[mt][ks] = *(const bf16x8*)(q + (size_t)(mt * 16 + lr) * 64 + ks * 32 + hi * 8);
#pragma unroll
  for (int nt = 0; nt < 4; ++nt)
#pragma unroll
    for (int ks = 0; ks < 2; ++ks)
      kb[nt][ks] = *(const bf16x8*)(k + (size_t)(nt * 16 + lr) * 64 + ks * 32 + hi * 8);

  f32x4 s[4][4];
#pragma unroll
  for (int mt = 0; mt < 4; ++mt)
#pragma unroll
    for (int nt = 0; nt < 4; ++nt) {
      s[mt][nt] = (f32x4){0.f, 0.f, 0.f, 0.f};
      s[mt][nt] = __builtin_amdgcn_mfma_f32_16x16x32_bf16(qa[mt][0], kb[nt][0], s[mt][nt], 0, 0, 0);
      s[mt][nt] = __builtin_amdgcn_mfma_f32_16x16x32_bf16(qa[mt][1], kb[nt][1], s[mt][nt], 0, 0, 0);
    }

#pragma unroll
  for (int mt = 0; mt < 4; ++mt)
#pragma unroll
    for (int nt = 0; nt < 4; ++nt)
#pragma unroll
      for (int rr = 0; rr < 4; ++rr)
        s[mt][nt][rr] += Bb[(mt * 16 + hi * 4 + rr) * 64 + nt * 16 + lr];

  float inv[4][4];
#pragma unroll
  for (int mt = 0; mt < 4; ++mt)
#pragma unroll
    for (int rr = 0; rr < 4; ++rr) {
      float m = fmaxf(fmaxf(s[mt][0][rr], s[mt][1][rr]),
                      fmaxf(s[mt][2][rr], s[mt][3][rr]));
      m = fmaxf(m, __shfl_xor(m, 1));
      m = fmaxf(m, __shfl_xor(m, 2));
      m = fmaxf(m, __shfl_xor(m, 4));
      m = fmaxf(m, __shfl_xor(m, 8));
      float sum = 0.f;
#pragma unroll
      for (int nt = 0; nt < 4; ++nt) {
        float e = __expf(s[mt][nt][rr] - m);
        s[mt][nt][rr] = e;
        sum += e;
      }
      sum += __shfl_xor(sum, 1);
      sum += __shfl_xor(sum, 2);
      sum += __shfl_xor(sum, 4);
      sum += __shfl_xor(sum, 8);
      inv[mt][rr] = 1.0f / sum;
    }

#pragma unroll
  for (int mt = 0; mt < 4; ++mt)
#pragma unroll
    for (int nt = 0; nt < 4; ++nt)
#pragma unroll
      for (int rr = 0; rr < 4; ++rr)
        P[(mt * 16 + hi * 4 + rr) * 72 + nt * 16 + lr] =
            f2bf(s[mt][nt][rr] * inv[mt][rr]);
  __syncthreads();

  bf16x8 pa[4][2], vb[4][2];
#pragma unroll
  for (int mt = 0; mt < 4; ++mt)
#pragma unroll
    for (int ks = 0; ks < 2; ++ks)
      pa[mt][ks] = *(const bf16x8*)(&P[(mt * 16 + lr) * 72 + ks * 32 + hi * 8]);
#pragma unroll
  for (int nt = 0; nt < 4; ++nt)
#pragma unroll
    for (int ks = 0; ks < 2; ++ks)
      vb[nt][ks] = *(const bf16x8*)(v + (size_t)(nt * 16 + lr) * 64 + ks * 32 + hi * 8);

  f32x4 o[4][4];
#pragma unroll
  for (int mt = 0; mt < 4; ++mt)
#pragma unroll
    for (int nt = 0; nt < 4; ++nt) {
      o[mt][nt] = (f32x4){0.f, 0.f, 0.f, 0.f};
      o[mt][nt] = __builtin_amdgcn_mfma_f32_16x16x32_bf16(pa[mt][0], vb[nt][0], o[mt][nt], 0, 0, 0);
      o[mt][nt] = __builtin_amdgcn_mfma_f32_16x16x32_bf16(pa[mt][1], vb[nt][1], o[mt][nt], 0, 0, 0);
    }

  float* op = out + (size_t)win * 32768 + h * 64;
#pragma unroll
  for (int mt = 0; mt < 4; ++mt)
#pragma unroll
    for (int nt = 0; nt < 4; ++nt)
#pragma unroll
      for (int rr = 0; rr < 4; ++rr)
        op[(size_t)(mt * 16 + hi * 4 + rr) * 512 + nt * 16 + lr] = o[mt][nt][rr];
}

extern "C" void kernel_launch(void* const* d_in, const int* in_sizes, int n_in,
                              void* d_out, int out_size, void* d_ws, size_t ws_size,
                              hipStream_t stream) {
  const float* x     = (const float*)d_in[0];
  const float* Wq    = (const float*)d_in[1];
  const float* bq    = (const float*)d_in[2];
  const float* Wk    = (const float*)d_in[3];
  const float* bk    = (const float*)d_in[4];
  const float* Wv    = (const float*)d_in[5];
  const float* bv    = (const float*)d_in[6];
  const float* Bbias = (const float*)d_in[7];
  float* out = (float*)d_out;

  // ws: Wc@0 | Xb@2MiB | Q@36MiB | K@68MiB | V^T@100MiB
  unsigned short* Wc = (unsigned short*)d_ws;
  unsigned short* Xb = (unsigned short*)((char*)d_ws + ((size_t)2 << 20));
  unsigned short* Q  = (unsigned short*)((char*)d_ws + ((size_t)36 << 20));
  unsigned short* K  = (unsigned short*)((char*)d_ws + ((size_t)68 << 20));
  unsigned short* V  = (unsigned short*)((char*)d_ws + ((size_t)100 << 20));

  prep_convert<<<dim3(8576), dim3(256), 0, stream>>>(x, Wq, Wk, Wv, Xb, Wc);
  qkv_gemm_256<<<dim3(768), dim3(512), 0, stream>>>(Xb, Wc, bq, bk, bv, Q, K, V);
  attn_win<<<dim3(4096), dim3(64), 0, stream>>>(Q, K, V, Bbias, out);
}

// Round 5
// 111.588 us; speedup vs baseline: 1.4187x; 1.0239x over previous
//
#include <hip/hip_runtime.h>
#include <hip/hip_bf16.h>

// B=8, C=512, H=W=64, NH=8, HD=64, WIN=64, NW=64.
// Token matrix = x viewed as [32768][512] fp32 (raw reshape).
//   phase 0: convert X -> bf16, W{q,k,v} -> Wcat bf16 [1536][512]
//   phase 1: QKV GEMM M=32768 K=512 N=1536 — 256x256 tile, BK=64, 8 waves,
//            drift schedule: 1 barrier/K-tile, stage-all-at-tile-start,
//            T2 swizzle (0 conflicts), LDS-staged coalesced epilogue
//   phase 2: per (window,head): S=Q@K^T(+bias), softmax, P@V
// ws: Wc@0 | Xb@2MiB | Q@36MiB | K@68MiB | V^T@100MiB (132MiB; fits).

typedef __attribute__((ext_vector_type(8))) short bf16x8;
typedef __attribute__((ext_vector_type(4))) float f32x4;

#define GLDS(gp, lp) __builtin_amdgcn_global_load_lds( \
    (const __attribute__((address_space(1))) unsigned int*)(gp), \
    (__attribute__((address_space(3))) unsigned int*)(lp), 16, 0, 0)

__device__ __forceinline__ unsigned short f2bf(float f) {
  union { float f; unsigned int u; } v; v.f = f;
  unsigned int r = v.u + 0x7fffu + ((v.u >> 16) & 1u);  // RNE
  return (unsigned short)(r >> 16);
}

// ---------- prep: X fp32->bf16 and W{q,k,v} -> Wcat bf16 ----------
__global__ __launch_bounds__(256) void prep_convert(
    const float* __restrict__ X, const float* __restrict__ Wq,
    const float* __restrict__ Wk, const float* __restrict__ Wv,
    unsigned short* __restrict__ Xb, unsigned short* __restrict__ Wc) {
  const unsigned int i = blockIdx.x * 256 + threadIdx.x;
  const float* src;
  unsigned short* dst;
  if (i < 2097152u) {                       // X: 16.7M floats, 8 per thread
    src = X + (size_t)i * 8;
    dst = Xb + (size_t)i * 8;
  } else {                                  // Wcat: [1536][512]
    const unsigned int j = i - 2097152u;    // < 98304
    const unsigned int e = j * 8;
    const unsigned int n = e >> 9, kk = e & 511;
    src = ((n < 512) ? Wq : (n < 1024 ? Wk : Wv)) + (size_t)(n & 511) * 512 + kk;
    dst = Wc + (size_t)n * 512 + kk;
  }
  float4 f0 = *(const float4*)(src);
  float4 f1 = *(const float4*)(src + 4);
  __align__(16) unsigned short u[8];
  u[0] = f2bf(f0.x); u[1] = f2bf(f0.y); u[2] = f2bf(f0.z); u[3] = f2bf(f0.w);
  u[4] = f2bf(f1.x); u[5] = f2bf(f1.y); u[6] = f2bf(f1.z); u[7] = f2bf(f1.w);
  *(bf16x8*)(dst) = *(const bf16x8*)(u);
}

// ---------- QKV GEMM: 256x256 tile, BK=64, 8 waves, drift schedule ----------
// Per K-tile: stage all 8 GLDS for t+1 into buf[t^1], then plain
// ds_read+MFMA (compiler-scheduled, waves drift), then vmcnt(0)+one barrier.
// Hazard proof: tile t-1's reads of buf[t^1] are lgkm-complete before its
// boundary barrier (every ds_read is consumed by an MFMA before the barrier
// in program order), so tile t's GLDS writes into buf[t^1] are safe.
__global__ __launch_bounds__(512, 2) void qkv_gemm_256(
    const unsigned short* __restrict__ Xb, const unsigned short* __restrict__ Wc,
    const float* __restrict__ bq, const float* __restrict__ bk,
    const float* __restrict__ bv,
    unsigned short* __restrict__ Qo, unsigned short* __restrict__ Ko,
    unsigned short* __restrict__ Vo) {
  __shared__ __align__(16) char LDS[131072];

  const int tid  = threadIdx.x;
  const int lane = tid & 63;
  const int wid  = tid >> 6;
  const int wm = wid >> 2, wn = wid & 3;

  // XCD-chunked swizzle: 768 = 8 x 96 works; n-tiles fastest within a chunk.
  const int work = (int)(blockIdx.x & 7) * 96 + (int)(blockIdx.x >> 3);
  const int bx = work % 6, by = work / 6;
  const int n0 = bx * 256, m0 = by * 256;

  // --- staging addressing (linear LDS dest; inverse-swizzled global source) ---
  const int lcol  = ((lane & 3) * 8) ^ ((lane >= 32) ? 16 : 0);   // elements
  const int arow0 = (wid >> 1) * 16 + (lane >> 2);                // j=0 row
  const int acol0 = (wid & 1) * 32 + lcol;                        // j=0 col

#define STAGE_A(half, tt) do { \
    const unsigned short* g = Xb + (size_t)(m0 + (half) * 128 + arow0) * 512 + (tt) * 64 + acol0; \
    char* l = LDS + ((tt) & 1) * 32768 + (half) * 16384 + wid * 1024; \
    GLDS(g, l); \
    GLDS(g + 64 * 512, l + 8192); \
  } while (0)

#define STAGE_B(half, tt) do { \
    const unsigned short* g = Wc + (size_t)(n0 + (half) * 128 + arow0) * 512 + (tt) * 64 + acol0; \
    char* l = LDS + 65536 + ((tt) & 1) * 32768 + (half) * 16384 + wid * 1024; \
    GLDS(g, l); \
    GLDS(g + 64 * 512, l + 8192); \
  } while (0)

  // --- fragment-read addressing (swizzled) ---
  const int sloff = (((lane & 15) * 64) + ((lane >> 4) * 16)) ^ ((lane & 8) ? 32 : 0);
  char* const Ab = LDS + wm * 16384 + sloff;
  char* const Bb2 = LDS + 65536 + (wn >> 1) * 16384 + sloff;
  const int bfr = (wn & 1) * 4;   // B frag index base within half

  f32x4 acc[8][4];
#pragma unroll
  for (int i = 0; i < 8; ++i)
#pragma unroll
    for (int j = 0; j < 4; ++j) acc[i][j] = (f32x4){0.f, 0.f, 0.f, 0.f};

#define LDA(mh, bo) do { \
    _Pragma("unroll") for (int mi = 0; mi < 4; ++mi) \
    _Pragma("unroll") for (int ks = 0; ks < 2; ++ks) \
      a[mi][ks] = *(const bf16x8*)(Ab + (bo) + ((mh) * 4 + mi) * 2048 + ks * 1024); \
  } while (0)

#define LDB(dst, nh, bo) do { \
    _Pragma("unroll") for (int ni = 0; ni < 2; ++ni) \
    _Pragma("unroll") for (int ks = 0; ks < 2; ++ks) \
      dst[ni][ks] = *(const bf16x8*)(Bb2 + (bo) + (bfr + (nh) * 2 + ni) * 2048 + ks * 1024); \
  } while (0)

#define MM(mh, nh, bb) do { \
    _Pragma("unroll") for (int mi = 0; mi < 4; ++mi) \
    _Pragma("unroll") for (int ni = 0; ni < 2; ++ni) \
    _Pragma("unroll") for (int ks = 0; ks < 2; ++ks) \
      acc[(mh) * 4 + mi][(nh) * 2 + ni] = __builtin_amdgcn_mfma_f32_16x16x32_bf16( \
          a[mi][ks], bb[ni][ks], acc[(mh) * 4 + mi][(nh) * 2 + ni], 0, 0, 0); \
  } while (0)

  // prologue: stage tile 0 into buf0
  STAGE_A(0, 0); STAGE_A(1, 0); STAGE_B(0, 0); STAGE_B(1, 0);
  asm volatile("s_waitcnt vmcnt(0)" ::: "memory");
  __builtin_amdgcn_s_barrier();

  for (int t = 0; t < 8; ++t) {
    const int bo = (t & 1) * 32768;
    if (t + 1 < 8) {                        // stage next tile into free buffer
      STAGE_A(0, t + 1); STAGE_A(1, t + 1);
      STAGE_B(0, t + 1); STAGE_B(1, t + 1);
    }
    {                                       // full-tile compute, no barriers
      bf16x8 a[4][2], b0[2][2], b1[2][2];
      LDA(0, bo); LDB(b0, 0, bo);
      MM(0, 0, b0);
      LDB(b1, 1, bo);
      MM(0, 1, b1);
      LDA(1, bo);
      MM(1, 1, b1);
      MM(1, 0, b0);
    }
    if (t + 1 < 8) asm volatile("s_waitcnt vmcnt(0)" ::: "memory");
    __builtin_amdgcn_s_barrier();
  }

  // ---- epilogue: LDS-staged, coalesced 16B stores ----
  // Wave's 128x64 output = 2 windows x 1 head. Per window: stage 64x64 bf16
  // tile in private 8KiB scratch with chunk-XOR (phys = r*64 + (d^((r&7)<<3))
  // shorts): writes 2-way (free), b128 row reads conflict-free, then 8
  // fully-coalesced 1KiB global store instrs.
  {
    const int p = n0 >> 9;                  // 0:Q 1:K 2:V (256-tile never spans)
    const float* bias = (p == 0) ? bq : (p == 1) ? bk : bv;
    const float qs = (p == 0) ? 0.125f : 1.0f;
    const int hi = lane >> 4, lr = lane & 15;
    const int h = ((n0 & 511) + wn * 64) >> 6;
    char* const scr = LDS + wid * 8192;
    float bsv[4];
#pragma unroll
    for (int ni = 0; ni < 4; ++ni)
      bsv[ni] = bias[(n0 & 511) + wn * 64 + ni * 16 + lr];

#pragma unroll
    for (int wh = 0; wh < 2; ++wh) {
      asm volatile("s_waitcnt lgkmcnt(0)" ::: "memory");  // WAR vs prev reads
      __builtin_amdgcn_sched_barrier(0);
      if (p < 2) {
        // T[t][d]: thread writes (t = f*16+hi*4+rr, d = ni*16+lr)
#pragma unroll
        for (int f = 0; f < 4; ++f)
#pragma unroll
          for (int ni = 0; ni < 4; ++ni) {
            const int d = ni * 16 + lr;
#pragma unroll
            for (int rr = 0; rr < 4; ++rr) {
              const int t = f * 16 + hi * 4 + rr;
              const int off = t * 64 + (d ^ ((t & 7) << 3));
              *(unsigned short*)(scr + off * 2) =
                  f2bf((acc[wh * 4 + f][ni][rr] + bsv[ni]) * qs);
            }
          }
      } else {
        // T'[d][t]: thread packs 4 consecutive t (rr) at fixed d -> b64
#pragma unroll
        for (int f = 0; f < 4; ++f)
#pragma unroll
          for (int ni = 0; ni < 4; ++ni) {
            const int d = ni * 16 + lr;
            const int t0 = f * 16 + hi * 4;
            ushort4 pk;
            pk.x = f2bf(acc[wh * 4 + f][ni][0] + bsv[ni]);
            pk.y = f2bf(acc[wh * 4 + f][ni][1] + bsv[ni]);
            pk.z = f2bf(acc[wh * 4 + f][ni][2] + bsv[ni]);
            pk.w = f2bf(acc[wh * 4 + f][ni][3] + bsv[ni]);
            const int off = d * 64 + (t0 ^ ((d & 7) << 3));
            *(ushort4*)(scr + off * 2) = pk;
          }
      }
      asm volatile("s_waitcnt lgkmcnt(0)" ::: "memory");  // writes -> readable
      __builtin_amdgcn_sched_barrier(0);
      const int win = (m0 + wm * 128 + wh * 64) >> 6;
      unsigned short* dst =
          ((p == 0) ? Qo : (p == 1) ? Ko : Vo) + (size_t)(win * 8 + h) * 4096;
#pragma unroll
      for (int i = 0; i < 8; ++i) {
        const int r = i * 8 + (lane >> 3);
        const int c = lane & 7;
        const int off = r * 64 + ((c ^ (r & 7)) * 8);
        bf16x8 row = *(const bf16x8*)(scr + off * 2);   // ds_read_b128
        *(bf16x8*)(dst + r * 64 + c * 8) = row;         // coalesced 16B store
      }
    }
  }
#undef STAGE_A
#undef STAGE_B
#undef LDA
#undef LDB
#undef MM
}

// ---------- attention: 1 wave per (window, head) ----------
__global__ __launch_bounds__(64) void attn_win(
    const unsigned short* __restrict__ Qp, const unsigned short* __restrict__ Kp,
    const unsigned short* __restrict__ Vp, const float* __restrict__ Bb,
    float* __restrict__ out) {
  __shared__ __align__(16) unsigned short P[64 * 72];
  const int lane = threadIdx.x;
  const int win = blockIdx.x >> 3;
  const int h   = blockIdx.x & 7;
  const size_t base = (size_t)(win * 8 + h) * 4096;
  const unsigned short* q = Qp + base;
  const unsigned short* k = Kp + base;
  const unsigned short* v = Vp + base;   // V^T: [d][t]
  const int lr = lane & 15;
  const int hi = lane >> 4;

  bf16x8 qa[4][2], kb[4][2];
#pragma unroll
  for (int mt = 0; mt < 4; ++mt)
#pragma unroll
    for (int ks = 0; ks < 2; ++ks)
      qa[mt][ks] = *(const bf16x8*)(q + (size_t)(mt * 16 + lr) * 64 + ks * 32 + hi * 8);
#pragma unroll
  for (int nt = 0; nt < 4; ++nt)
#pragma unroll
    for (int ks = 0; ks < 2; ++ks)
      kb[nt][ks] = *(const bf16x8*)(k + (size_t)(nt * 16 + lr) * 64 + ks * 32 + hi * 8);

  f32x4 s[4][4];
#pragma unroll
  for (int mt = 0; mt < 4; ++mt)
#pragma unroll
    for (int nt = 0; nt < 4; ++nt) {
      s[mt][nt] = (f32x4){0.f, 0.f, 0.f, 0.f};
      s[mt][nt] = __builtin_amdgcn_mfma_f32_16x16x32_bf16(qa[mt][0], kb[nt][0], s[mt][nt], 0, 0, 0);
      s[mt][nt] = __builtin_amdgcn_mfma_f32_16x16x32_bf16(qa[mt][1], kb[nt][1], s[mt][nt], 0, 0, 0);
    }

#pragma unroll
  for (int mt = 0; mt < 4; ++mt)
#pragma unroll
    for (int nt = 0; nt < 4; ++nt)
#pragma unroll
      for (int rr = 0; rr < 4; ++rr)
        s[mt][nt][rr] += Bb[(mt * 16 + hi * 4 + rr) * 64 + nt * 16 + lr];

  float inv[4][4];
#pragma unroll
  for (int mt = 0; mt < 4; ++mt)
#pragma unroll
    for (int rr = 0; rr < 4; ++rr) {
      float m = fmaxf(fmaxf(s[mt][0][rr], s[mt][1][rr]),
                      fmaxf(s[mt][2][rr], s[mt][3][rr]));
      m = fmaxf(m, __shfl_xor(m, 1));
      m = fmaxf(m, __shfl_xor(m, 2));
      m = fmaxf(m, __shfl_xor(m, 4));
      m = fmaxf(m, __shfl_xor(m, 8));
      float sum = 0.f;
#pragma unroll
      for (int nt = 0; nt < 4; ++nt) {
        float e = __expf(s[mt][nt][rr] - m);
        s[mt][nt][rr] = e;
        sum += e;
      }
      sum += __shfl_xor(sum, 1);
      sum += __shfl_xor(sum, 2);
      sum += __shfl_xor(sum, 4);
      sum += __shfl_xor(sum, 8);
      inv[mt][rr] = 1.0f / sum;
    }

#pragma unroll
  for (int mt = 0; mt < 4; ++mt)
#pragma unroll
    for (int nt = 0; nt < 4; ++nt)
#pragma unroll
      for (int rr = 0; rr < 4; ++rr)
        P[(mt * 16 + hi * 4 + rr) * 72 + nt * 16 + lr] =
            f2bf(s[mt][nt][rr] * inv[mt][rr]);
  __syncthreads();

  bf16x8 pa[4][2], vb[4][2];
#pragma unroll
  for (int mt = 0; mt < 4; ++mt)
#pragma unroll
    for (int ks = 0; ks < 2; ++ks)
      pa[mt][ks] = *(const bf16x8*)(&P[(mt * 16 + lr) * 72 + ks * 32 + hi * 8]);
#pragma unroll
  for (int nt = 0; nt < 4; ++nt)
#pragma unroll
    for (int ks = 0; ks < 2; ++ks)
      vb[nt][ks] = *(const bf16x8*)(v + (size_t)(nt * 16 + lr) * 64 + ks * 32 + hi * 8);

  f32x4 o[4][4];
#pragma unroll
  for (int mt = 0; mt < 4; ++mt)
#pragma unroll
    for (int nt = 0; nt < 4; ++nt) {
      o[mt][nt] = (f32x4){0.f, 0.f, 0.f, 0.f};
      o[mt][nt] = __builtin_amdgcn_mfma_f32_16x16x32_bf16(pa[mt][0], vb[nt][0], o[mt][nt], 0, 0, 0);
      o[mt][nt] = __builtin_amdgcn_mfma_f32_16x16x32_bf16(pa[mt][1], vb[nt][1], o[mt][nt], 0, 0, 0);
    }

  float* op = out + (size_t)win * 32768 + h * 64;
#pragma unroll
  for (int mt = 0; mt < 4; ++mt)
#pragma unroll
    for (int nt = 0; nt < 4; ++nt)
#pragma unroll
      for (int rr = 0; rr < 4; ++rr)
        op[(size_t)(mt * 16 + hi * 4 + rr) * 512 + nt * 16 + lr] = o[mt][nt][rr];
}

extern "C" void kernel_launch(void* const* d_in, const int* in_sizes, int n_in,
                              void* d_out, int out_size, void* d_ws, size_t ws_size,
                              hipStream_t stream) {
  const float* x     = (const float*)d_in[0];
  const float* Wq    = (const float*)d_in[1];
  const float* bq    = (const float*)d_in[2];
  const float* Wk    = (const float*)d_in[3];
  const float* bk    = (const float*)d_in[4];
  const float* Wv    = (const float*)d_in[5];
  const float* bv    = (const float*)d_in[6];
  const float* Bbias = (const float*)d_in[7];
  float* out = (float*)d_out;

  // ws: Wc@0 | Xb@2MiB | Q@36MiB | K@68MiB | V^T@100MiB
  unsigned short* Wc = (unsigned short*)d_ws;
  unsigned short* Xb = (unsigned short*)((char*)d_ws + ((size_t)2 << 20));
  unsigned short* Q  = (unsigned short*)((char*)d_ws + ((size_t)36 << 20));
  unsigned short* K  = (unsigned short*)((char*)d_ws + ((size_t)68 << 20));
  unsigned short* V  = (unsigned short*)((char*)d_ws + ((size_t)100 << 20));

  prep_convert<<<dim3(8576), dim3(256), 0, stream>>>(x, Wq, Wk, Wv, Xb, Wc);
  qkv_gemm_256<<<dim3(768), dim3(512), 0, stream>>>(Xb, Wc, bq, bk, bv, Q, K, V);
  attn_win<<<dim3(4096), dim3(64), 0, stream>>>(Q, K, V, Bbias, out);
}